// Round 1
// baseline (705.184 us; speedup 1.0000x reference)
//
#include <hip/hip_runtime.h>
#include <math.h>

#define Bn   128
#define Cn   2048
#define Hn   24
#define Wn   12
#define HID  768
#define NIN  1536
#define NST  16
#define DTR  48
#define Ln   9
#define Mn   (Bn*Ln)   // 1152

// ---------------- pooling: x (B,C,24,12) -> tok (B*9, C), p = i*3+j ----------------
__global__ __launch_bounds__(256) void pool_kernel(const float* __restrict__ x,
                                                   float* __restrict__ tok) {
  int idx = blockIdx.x * 256 + threadIdx.x;           // over B*C
  if (idx >= Bn * Cn) return;
  int b = idx / Cn, c = idx - b * Cn;
  const float4* p = reinterpret_cast<const float4*>(x + (size_t)idx * (Hn * Wn));
  float s[9] = {0,0,0,0,0,0,0,0,0};
  #pragma unroll
  for (int h = 0; h < 24; ++h) {
    int i = h >> 3;
    #pragma unroll
    for (int j = 0; j < 3; ++j) {
      float4 v = p[h * 3 + j];                        // 4 consecutive w == one j-block
      s[i * 3 + j] += (v.x + v.y) + (v.z + v.w);
    }
  }
  #pragma unroll
  for (int pp = 0; pp < 9; ++pp)
    tok[((size_t)(b * Ln + pp)) * Cn + c] = s[pp] * (1.0f / 32.0f);
}

// ---------------- generic fp32 tiled GEMM: C = A(M,K;lda) * B(K,N) [+bias][softplus] ----
template<int ACT>
__global__ __launch_bounds__(256) void gemm_kernel(const float* __restrict__ A, int lda,
    const float* __restrict__ Bm, const float* __restrict__ bias, float* __restrict__ Cm,
    int M, int N, int K) {
  __shared__ float As[16][68];
  __shared__ float Bs[16][68];
  int t  = threadIdx.x;
  int bm = blockIdx.y * 64, bn = blockIdx.x * 64;
  int tx = t & 15, ty = t >> 4;
  float acc[4][4] = {};
  int ar = t >> 2, ak = (t & 3) * 4;   // A: row ar, k-chunk ak (float4)
  int br = t >> 4, bc = (t & 15) * 4;  // B: k-row br, col-chunk bc (float4)
  for (int k0 = 0; k0 < K; k0 += 16) {   // all K are multiples of 16
    float4 av = make_float4(0.f, 0.f, 0.f, 0.f);
    if (bm + ar < M)
      av = *reinterpret_cast<const float4*>(A + (size_t)(bm + ar) * lda + k0 + ak);
    As[ak + 0][ar] = av.x; As[ak + 1][ar] = av.y;
    As[ak + 2][ar] = av.z; As[ak + 3][ar] = av.w;
    float4 bv = make_float4(0.f, 0.f, 0.f, 0.f);
    if (bn + bc < N)       // N is a multiple of 4 always
      bv = *reinterpret_cast<const float4*>(Bm + (size_t)(k0 + br) * N + bn + bc);
    *reinterpret_cast<float4*>(&Bs[br][bc]) = bv;
    __syncthreads();
    #pragma unroll
    for (int kk = 0; kk < 16; ++kk) {
      float a0[4], b0[4];
      #pragma unroll
      for (int i = 0; i < 4; ++i) a0[i] = As[kk][ty * 4 + i];
      #pragma unroll
      for (int j = 0; j < 4; ++j) b0[j] = Bs[kk][tx * 4 + j];
      #pragma unroll
      for (int i = 0; i < 4; ++i)
        #pragma unroll
        for (int j = 0; j < 4; ++j)
          acc[i][j] = fmaf(a0[i], b0[j], acc[i][j]);
    }
    __syncthreads();
  }
  #pragma unroll
  for (int i = 0; i < 4; ++i) {
    int row = bm + ty * 4 + i;
    if (row >= M) continue;
    #pragma unroll
    for (int j = 0; j < 4; ++j) {
      int col = bn + tx * 4 + j;
      if (col >= N) continue;
      float v = acc[i][j];
      if (bias) v += bias[col];
      if (ACT == 1) v = fmaxf(v, 0.0f) + log1pf(expf(-fabsf(v)));  // stable softplus
      Cm[(size_t)row * N + col] = v;
    }
  }
}

// ---------------- LayerNorm over 768 per row ----------------
__global__ __launch_bounds__(256) void ln_kernel(const float* __restrict__ in,
    const float* __restrict__ g, const float* __restrict__ be, float* __restrict__ out) {
  int row = blockIdx.x;
  const float* r = in + (size_t)row * HID;
  int t = threadIdx.x;
  float v0 = r[t], v1 = r[t + 256], v2 = r[t + 512];
  float s  = v0 + v1 + v2;
  float s2 = v0 * v0 + v1 * v1 + v2 * v2;
  #pragma unroll
  for (int o = 32; o > 0; o >>= 1) {
    s  += __shfl_down(s,  o, 64);
    s2 += __shfl_down(s2, o, 64);
  }
  __shared__ float red[8];
  int wid = t >> 6, lane = t & 63;
  if (lane == 0) { red[wid] = s; red[4 + wid] = s2; }
  __syncthreads();
  float S  = red[0] + red[1] + red[2] + red[3];
  float S2 = red[4] + red[5] + red[6] + red[7];
  float mu  = S * (1.0f / HID);
  float var = S2 * (1.0f / HID) - mu * mu;
  float inv = rsqrtf(var + 1e-5f);
  out[(size_t)row * HID + t      ] = (v0 - mu) * inv * g[t      ] + be[t      ];
  out[(size_t)row * HID + t + 256] = (v1 - mu) * inv * g[t + 256] + be[t + 256];
  out[(size_t)row * HID + t + 512] = (v2 - mu) * inv * g[t + 512] + be[t + 512];
}

// ---------------- depthwise conv (k=3, zero pad) + silu; xs = xz[...,:NIN] ----------------
__global__ __launch_bounds__(256) void conv_silu_kernel(const float* __restrict__ xz,
    const float* __restrict__ w, const float* __restrict__ cb, float* __restrict__ xc) {
  int idx = blockIdx.x * 256 + threadIdx.x;           // over Mn*NIN
  if (idx >= Mn * NIN) return;
  int d  = idx % NIN;
  int bp = idx / NIN;
  int p = bp % Ln, b = bp / Ln;
  const float* base = xz + (size_t)(b * Ln) * (2 * NIN) + d;
  float acc = cb[d];
  float w0 = w[d * 3], w1 = w[d * 3 + 1], w2 = w[d * 3 + 2];
  if (p > 0)      acc += base[(size_t)(p - 1) * (2 * NIN)] * w0;
  acc += base[(size_t)p * (2 * NIN)] * w1;
  if (p < Ln - 1) acc += base[(size_t)(p + 1) * (2 * NIN)] * w2;
  float sg = 1.0f / (1.0f + expf(-acc));
  xc[idx] = acc * sg;
}

// ---------------- selective scan (L=9) + D-residual + z-gate ----------------
__global__ __launch_bounds__(256) void scan_kernel(const float* __restrict__ delta,
    const float* __restrict__ dbc, const float* __restrict__ xcb,
    const float* __restrict__ A_log, const float* __restrict__ Dp,
    const float* __restrict__ xz, float* __restrict__ ya) {
  __shared__ float Bs[Ln][NST], Cs[Ln][NST];
  int b      = blockIdx.x / (NIN / 256);
  int dchunk = blockIdx.x % (NIN / 256);
  int t = threadIdx.x;
  if (t < Ln * NST) {
    int p = t / NST, n = t % NST;
    const float* row = dbc + (size_t)(b * Ln + p) * (DTR + 2 * NST);
    Bs[p][n] = row[DTR + n];
    Cs[p][n] = row[DTR + NST + n];
  }
  __syncthreads();
  int d = dchunk * 256 + t;
  float Ar[NST];
  #pragma unroll
  for (int n = 0; n < NST; ++n) Ar[n] = -expf(A_log[(size_t)d * NST + n]);
  float s[NST];
  #pragma unroll
  for (int n = 0; n < NST; ++n) s[n] = 0.0f;
  float Dv = Dp[d];
  for (int p = 0; p < Ln; ++p) {
    size_t off = (size_t)(b * Ln + p) * NIN + d;
    float dl = delta[off];
    float u  = xcb[off];
    float du = dl * u;
    float y = 0.0f;
    #pragma unroll
    for (int n = 0; n < NST; ++n) {
      float dA = expf(dl * Ar[n]);
      s[n] = dA * s[n] + du * Bs[p][n];
      y += s[n] * Cs[p][n];
    }
    float zv = xz[(size_t)(b * Ln + p) * (2 * NIN) + NIN + d];
    float sz = zv / (1.0f + expf(-zv));               // silu(z)
    ya[off] = (y + u * Dv) * sz;
  }
}

// ---------------- transpose + bilinear resize (3,3) -> (24,12), half-pixel + clamp ----------
__global__ __launch_bounds__(256) void resize_kernel(const float* __restrict__ o9,
                                                     float* __restrict__ out) {
  int idx = blockIdx.x * 256 + threadIdx.x;           // over B*C*24
  if (idx >= Bn * Cn * Hn) return;
  int y  = idx % Hn;
  int bc = idx / Hn;
  int c = bc % Cn, b = bc / Cn;
  float v[9];
  #pragma unroll
  for (int p = 0; p < 9; ++p) v[p] = o9[(size_t)(b * Ln + p) * Cn + c];
  float fy  = (y + 0.5f) * 0.125f - 0.5f;
  float fyf = floorf(fy);
  float wy  = fy - fyf;
  int y0 = (int)fyf, y1 = y0 + 1;
  y0 = min(2, max(0, y0)); y1 = min(2, max(0, y1));
  float rr[3];
  #pragma unroll
  for (int j = 0; j < 3; ++j) rr[j] = v[y0 * 3 + j] * (1.0f - wy) + v[y1 * 3 + j] * wy;
  float ov[12];
  #pragma unroll
  for (int xo = 0; xo < 12; ++xo) {
    float fx  = (xo + 0.5f) * 0.25f - 0.5f;
    float fxf = floorf(fx);
    float wx  = fx - fxf;
    int x0 = (int)fxf, x1 = x0 + 1;
    x0 = min(2, max(0, x0)); x1 = min(2, max(0, x1));
    ov[xo] = rr[x0] * (1.0f - wx) + rr[x1] * wx;
  }
  float4* op = reinterpret_cast<float4*>(out + (size_t)idx * 12);
  op[0] = make_float4(ov[0], ov[1], ov[2],  ov[3]);
  op[1] = make_float4(ov[4], ov[5], ov[6],  ov[7]);
  op[2] = make_float4(ov[8], ov[9], ov[10], ov[11]);
}

extern "C" void kernel_launch(void* const* d_in, const int* in_sizes, int n_in,
                              void* d_out, int out_size, void* d_ws, size_t ws_size,
                              hipStream_t stream) {
  const float* x        = (const float*)d_in[0];
  const float* pe_w     = (const float*)d_in[1];
  const float* pe_b     = (const float*)d_in[2];
  const float* ln_g     = (const float*)d_in[3];
  const float* ln_b     = (const float*)d_in[4];
  const float* in_w     = (const float*)d_in[5];
  const float* conv_w   = (const float*)d_in[6];
  const float* conv_b   = (const float*)d_in[7];
  const float* A_log    = (const float*)d_in[8];
  const float* xproj_w  = (const float*)d_in[9];
  const float* dtproj_w = (const float*)d_in[10];
  const float* dtproj_b = (const float*)d_in[11];
  const float* D_param  = (const float*)d_in[12];
  const float* out_w    = (const float*)d_in[13];
  float* out = (float*)d_out;
  float* ws  = (float*)d_ws;

  // workspace layout (floats), with lifetime-based aliasing; peak ~41.7 MB
  float* tok   = ws;             // 2359296  (Mn x Cn)
  float* t1    = ws + 2359296;   // 884736   (Mn x HID)
  float* xz    = ws + 3244032;   // 3538944  (Mn x 2*NIN)
  float* xc    = ws + 6782976;   // 1769472  (Mn x NIN)
  float* dbc   = ws + 8552448;   // 92160    (Mn x 80)
  float* delta = ws + 8644608;   // 1769472  (Mn x NIN)
  float* h     = tok;            // alias: tok dead after gemm1
  float* ya    = tok;            // alias: h dead after gemm(in_w)
  float* o9    = xz;             // alias: xz (z part) dead after scan

  pool_kernel<<<(Bn * Cn) / 256, 256, 0, stream>>>(x, tok);
  gemm_kernel<0><<<dim3(HID / 64, Mn / 64), 256, 0, stream>>>(
      tok, Cn, pe_w, pe_b, t1, Mn, HID, Cn);
  ln_kernel<<<Mn, 256, 0, stream>>>(t1, ln_g, ln_b, h);
  gemm_kernel<0><<<dim3(2 * NIN / 64, Mn / 64), 256, 0, stream>>>(
      h, HID, in_w, nullptr, xz, Mn, 2 * NIN, HID);
  conv_silu_kernel<<<(Mn * NIN) / 256, 256, 0, stream>>>(xz, conv_w, conv_b, xc);
  gemm_kernel<0><<<dim3(2, Mn / 64), 256, 0, stream>>>(
      xc, NIN, xproj_w, nullptr, dbc, Mn, DTR + 2 * NST, NIN);
  gemm_kernel<1><<<dim3(NIN / 64, Mn / 64), 256, 0, stream>>>(
      dbc, DTR + 2 * NST, dtproj_w, dtproj_b, delta, Mn, NIN, DTR);
  scan_kernel<<<Bn * (NIN / 256), 256, 0, stream>>>(
      delta, dbc, xc, A_log, D_param, xz, ya);
  gemm_kernel<0><<<dim3(Cn / 64, Mn / 64), 256, 0, stream>>>(
      ya, NIN, out_w, nullptr, o9, Mn, Cn, NIN);
  resize_kernel<<<(Bn * Cn * Hn) / 256, 256, 0, stream>>>(o9, out);
}

// Round 2
// 547.030 us; speedup vs baseline: 1.2891x; 1.2891x over previous
//
#include <hip/hip_runtime.h>
#include <math.h>

#define Bn   128
#define Cn   2048
#define Hn   24
#define Wn   12
#define HID  768
#define NIN  1536
#define NST  16
#define DTR  48
#define Ln   9
#define Mn   (Bn*Ln)   // 1152

typedef __bf16 bf16x8 __attribute__((ext_vector_type(8)));
typedef float  f32x4  __attribute__((ext_vector_type(4)));

__device__ __forceinline__ unsigned short f2bf(float f) {
  unsigned u = __float_as_uint(f);
  u += 0x7fffu + ((u >> 16) & 1u);           // round-to-nearest-even
  return (unsigned short)(u >> 16);
}
__device__ __forceinline__ float bf2f(unsigned short h) {
  return __uint_as_float(((unsigned)h) << 16);
}
__device__ __forceinline__ void split_bf(float f, unsigned short& hi, unsigned short& lo) {
  hi = f2bf(f);
  lo = f2bf(f - bf2f(hi));
}

// ---------------- pooling: x (B,C,24,12) -> tok (B*9, C) as bf16 hi/lo ----------------
__global__ __launch_bounds__(256) void pool_kernel(const float* __restrict__ x,
    unsigned short* __restrict__ thi, unsigned short* __restrict__ tlo) {
  int idx = blockIdx.x * 256 + threadIdx.x;           // over B*C
  if (idx >= Bn * Cn) return;
  int b = idx / Cn, c = idx - b * Cn;
  const float4* p = reinterpret_cast<const float4*>(x + (size_t)idx * (Hn * Wn));
  float s[9] = {0,0,0,0,0,0,0,0,0};
  #pragma unroll
  for (int h = 0; h < 24; ++h) {
    int i = h >> 3;
    #pragma unroll
    for (int j = 0; j < 3; ++j) {
      float4 v = p[h * 3 + j];
      s[i * 3 + j] += (v.x + v.y) + (v.z + v.w);
    }
  }
  #pragma unroll
  for (int pp = 0; pp < 9; ++pp) {
    float v = s[pp] * (1.0f / 32.0f);
    unsigned short hi, lo;
    split_bf(v, hi, lo);
    size_t o = ((size_t)(b * Ln + pp)) * Cn + c;
    thi[o] = hi; tlo[o] = lo;
  }
}

// ---------------- fp32 W[K][N] -> transposed bf16-split WT[N][K] ----------------
__global__ __launch_bounds__(256) void tconv_kernel(const float* __restrict__ W,
    int K, int N, unsigned short* __restrict__ Thi, unsigned short* __restrict__ Tlo) {
  __shared__ float tile[32][33];
  int nb = blockIdx.x, kb = blockIdx.y;
  int t = threadIdx.x;
  int kl = t >> 3, n4 = (t & 7) * 4;
  float4 v = *reinterpret_cast<const float4*>(W + (size_t)(kb * 32 + kl) * N + nb * 32 + n4);
  tile[kl][n4] = v.x; tile[kl][n4 + 1] = v.y; tile[kl][n4 + 2] = v.z; tile[kl][n4 + 3] = v.w;
  __syncthreads();
  int nl = t >> 3, k4 = (t & 7) * 4;
  unsigned short hi[4], lo[4];
  #pragma unroll
  for (int i = 0; i < 4; ++i) split_bf(tile[k4 + i][nl], hi[i], lo[i]);
  size_t o = (size_t)(nb * 32 + nl) * K + kb * 32 + k4;
  uint2 ph, pl;
  ph.x = (unsigned)hi[0] | ((unsigned)hi[1] << 16);
  ph.y = (unsigned)hi[2] | ((unsigned)hi[3] << 16);
  pl.x = (unsigned)lo[0] | ((unsigned)lo[1] << 16);
  pl.y = (unsigned)lo[2] | ((unsigned)lo[3] << 16);
  *reinterpret_cast<uint2*>(Thi + o) = ph;
  *reinterpret_cast<uint2*>(Tlo + o) = pl;
}

// ------------- split-bf16 MFMA GEMM: C(M,N) = A(M,K) * B^T(N,K), fp32 out, opt bias -------------
// A,B given as bf16 hi/lo pairs. 128x128 tile, BK=32, 4 waves of 64x64.
template<int BIAS>
__global__ __launch_bounds__(256) void mgemm_kernel(
    const unsigned short* __restrict__ Ahi, const unsigned short* __restrict__ Alo,
    const unsigned short* __restrict__ Bhi, const unsigned short* __restrict__ Blo,
    const float* __restrict__ bias, float* __restrict__ C, int M, int N, int K) {
  __shared__ unsigned short As[2][128][32];
  __shared__ unsigned short Bs[2][128][32];
  int t = threadIdx.x;
  int bm = blockIdx.y * 128, bn = blockIdx.x * 128;
  int wave = t >> 6, lane = t & 63;
  int wr = (wave >> 1) * 64, wc = (wave & 1) * 64;
  int lr = lane & 15, lk = lane >> 4;

  f32x4 acc[4][4];
  #pragma unroll
  for (int m = 0; m < 4; ++m)
    #pragma unroll
    for (int n = 0; n < 4; ++n) acc[m][n] = {0.f, 0.f, 0.f, 0.f};

  int r0  = t >> 2, ko0 = t & 3;                 // staging: chunk (row, 8-half chunk)
  int swz = (ko0 ^ (r0 & 3)) * 8;                // (r0+64)&3 == r0&3

  for (int k0 = 0; k0 < K; k0 += 32) {
    size_t gA0 = (size_t)(bm + r0) * K + k0 + ko0 * 8;
    size_t gA1 = gA0 + (size_t)64 * K;
    size_t gB0 = (size_t)(bn + r0) * K + k0 + ko0 * 8;
    size_t gB1 = gB0 + (size_t)64 * K;
    float4 vah0 = *reinterpret_cast<const float4*>(Ahi + gA0);
    float4 vah1 = *reinterpret_cast<const float4*>(Ahi + gA1);
    float4 val0 = *reinterpret_cast<const float4*>(Alo + gA0);
    float4 val1 = *reinterpret_cast<const float4*>(Alo + gA1);
    float4 vbh0 = *reinterpret_cast<const float4*>(Bhi + gB0);
    float4 vbh1 = *reinterpret_cast<const float4*>(Bhi + gB1);
    float4 vbl0 = *reinterpret_cast<const float4*>(Blo + gB0);
    float4 vbl1 = *reinterpret_cast<const float4*>(Blo + gB1);
    __syncthreads();   // previous iteration's reads done before overwrite
    *reinterpret_cast<float4*>(&As[0][r0     ][swz]) = vah0;
    *reinterpret_cast<float4*>(&As[0][r0 + 64][swz]) = vah1;
    *reinterpret_cast<float4*>(&As[1][r0     ][swz]) = val0;
    *reinterpret_cast<float4*>(&As[1][r0 + 64][swz]) = val1;
    *reinterpret_cast<float4*>(&Bs[0][r0     ][swz]) = vbh0;
    *reinterpret_cast<float4*>(&Bs[0][r0 + 64][swz]) = vbh1;
    *reinterpret_cast<float4*>(&Bs[1][r0     ][swz]) = vbl0;
    *reinterpret_cast<float4*>(&Bs[1][r0 + 64][swz]) = vbl1;
    __syncthreads();

    bf16x8 a_hi[4], a_lo[4], b_hi[4], b_lo[4];
    #pragma unroll
    for (int m = 0; m < 4; ++m) {
      int arow = wr + m * 16 + lr;
      int asw  = (lk ^ (arow & 3)) * 8;
      a_hi[m] = *reinterpret_cast<const bf16x8*>(&As[0][arow][asw]);
      a_lo[m] = *reinterpret_cast<const bf16x8*>(&As[1][arow][asw]);
    }
    #pragma unroll
    for (int n = 0; n < 4; ++n) {
      int brow = wc + n * 16 + lr;
      int bsw  = (lk ^ (brow & 3)) * 8;
      b_hi[n] = *reinterpret_cast<const bf16x8*>(&Bs[0][brow][bsw]);
      b_lo[n] = *reinterpret_cast<const bf16x8*>(&Bs[1][brow][bsw]);
    }
    #pragma unroll
    for (int m = 0; m < 4; ++m)
      #pragma unroll
      for (int n = 0; n < 4; ++n) {
        acc[m][n] = __builtin_amdgcn_mfma_f32_16x16x32_bf16(a_hi[m], b_hi[n], acc[m][n], 0, 0, 0);
        acc[m][n] = __builtin_amdgcn_mfma_f32_16x16x32_bf16(a_hi[m], b_lo[n], acc[m][n], 0, 0, 0);
        acc[m][n] = __builtin_amdgcn_mfma_f32_16x16x32_bf16(a_lo[m], b_hi[n], acc[m][n], 0, 0, 0);
      }
  }

  #pragma unroll
  for (int m = 0; m < 4; ++m)
    #pragma unroll
    for (int n = 0; n < 4; ++n) {
      int col = bn + wc + n * 16 + lr;
      float bv = BIAS ? bias[col] : 0.0f;
      #pragma unroll
      for (int r = 0; r < 4; ++r) {
        int row = bm + wr + m * 16 + lk * 4 + r;
        C[(size_t)row * N + col] = acc[m][n][r] + bv;
      }
    }
}

// ---------------- generic fp32 tiled GEMM (small GEMMs only) ----------------
template<int ACT>
__global__ __launch_bounds__(256) void gemm_kernel(const float* __restrict__ A, int lda,
    const float* __restrict__ Bm, const float* __restrict__ bias, float* __restrict__ Cm,
    int M, int N, int K) {
  __shared__ float As[16][68];
  __shared__ float Bs[16][68];
  int t  = threadIdx.x;
  int bm = blockIdx.y * 64, bn = blockIdx.x * 64;
  int tx = t & 15, ty = t >> 4;
  float acc[4][4] = {};
  int ar = t >> 2, ak = (t & 3) * 4;
  int br = t >> 4, bc = (t & 15) * 4;
  for (int k0 = 0; k0 < K; k0 += 16) {
    float4 av = make_float4(0.f, 0.f, 0.f, 0.f);
    if (bm + ar < M)
      av = *reinterpret_cast<const float4*>(A + (size_t)(bm + ar) * lda + k0 + ak);
    As[ak + 0][ar] = av.x; As[ak + 1][ar] = av.y;
    As[ak + 2][ar] = av.z; As[ak + 3][ar] = av.w;
    float4 bv = make_float4(0.f, 0.f, 0.f, 0.f);
    if (bn + bc < N)
      bv = *reinterpret_cast<const float4*>(Bm + (size_t)(k0 + br) * N + bn + bc);
    *reinterpret_cast<float4*>(&Bs[br][bc]) = bv;
    __syncthreads();
    #pragma unroll
    for (int kk = 0; kk < 16; ++kk) {
      float a0[4], b0[4];
      #pragma unroll
      for (int i = 0; i < 4; ++i) a0[i] = As[kk][ty * 4 + i];
      #pragma unroll
      for (int j = 0; j < 4; ++j) b0[j] = Bs[kk][tx * 4 + j];
      #pragma unroll
      for (int i = 0; i < 4; ++i)
        #pragma unroll
        for (int j = 0; j < 4; ++j)
          acc[i][j] = fmaf(a0[i], b0[j], acc[i][j]);
    }
    __syncthreads();
  }
  #pragma unroll
  for (int i = 0; i < 4; ++i) {
    int row = bm + ty * 4 + i;
    if (row >= M) continue;
    #pragma unroll
    for (int j = 0; j < 4; ++j) {
      int col = bn + tx * 4 + j;
      if (col >= N) continue;
      float v = acc[i][j];
      if (bias) v += bias[col];
      if (ACT == 1) v = fmaxf(v, 0.0f) + log1pf(expf(-fabsf(v)));
      Cm[(size_t)row * N + col] = v;
    }
  }
}

// ---------------- LayerNorm over 768, writes bf16-split h ----------------
__global__ __launch_bounds__(256) void ln_kernel(const float* __restrict__ in,
    const float* __restrict__ g, const float* __restrict__ be,
    unsigned short* __restrict__ hhi, unsigned short* __restrict__ hlo) {
  int row = blockIdx.x;
  const float* r = in + (size_t)row * HID;
  int t = threadIdx.x;
  float v0 = r[t], v1 = r[t + 256], v2 = r[t + 512];
  float s  = v0 + v1 + v2;
  float s2 = v0 * v0 + v1 * v1 + v2 * v2;
  #pragma unroll
  for (int o = 32; o > 0; o >>= 1) {
    s  += __shfl_down(s,  o, 64);
    s2 += __shfl_down(s2, o, 64);
  }
  __shared__ float red[8];
  int wid = t >> 6, lane = t & 63;
  if (lane == 0) { red[wid] = s; red[4 + wid] = s2; }
  __syncthreads();
  float S  = red[0] + red[1] + red[2] + red[3];
  float S2 = red[4] + red[5] + red[6] + red[7];
  float mu  = S * (1.0f / HID);
  float var = S2 * (1.0f / HID) - mu * mu;
  float inv = rsqrtf(var + 1e-5f);
  #pragma unroll
  for (int q = 0; q < 3; ++q) {
    int c = t + q * 256;
    float v = (q == 0 ? v0 : (q == 1 ? v1 : v2));
    float hv = (v - mu) * inv * g[c] + be[c];
    unsigned short hi, lo;
    split_bf(hv, hi, lo);
    size_t o = (size_t)row * HID + c;
    hhi[o] = hi; hlo[o] = lo;
  }
}

// ---------------- depthwise conv (k=3) + silu ----------------
__global__ __launch_bounds__(256) void conv_silu_kernel(const float* __restrict__ xz,
    const float* __restrict__ w, const float* __restrict__ cb, float* __restrict__ xc) {
  int idx = blockIdx.x * 256 + threadIdx.x;
  if (idx >= Mn * NIN) return;
  int d  = idx % NIN;
  int bp = idx / NIN;
  int p = bp % Ln, b = bp / Ln;
  const float* base = xz + (size_t)(b * Ln) * (2 * NIN) + d;
  float acc = cb[d];
  float w0 = w[d * 3], w1 = w[d * 3 + 1], w2 = w[d * 3 + 2];
  if (p > 0)      acc += base[(size_t)(p - 1) * (2 * NIN)] * w0;
  acc += base[(size_t)p * (2 * NIN)] * w1;
  if (p < Ln - 1) acc += base[(size_t)(p + 1) * (2 * NIN)] * w2;
  float sg = 1.0f / (1.0f + expf(-acc));
  xc[idx] = acc * sg;
}

// ---------------- selective scan + D-residual + z-gate, writes bf16-split ya ----------------
__global__ __launch_bounds__(256) void scan_kernel(const float* __restrict__ delta,
    const float* __restrict__ dbc, const float* __restrict__ xcb,
    const float* __restrict__ A_log, const float* __restrict__ Dp,
    const float* __restrict__ xz,
    unsigned short* __restrict__ yhi, unsigned short* __restrict__ ylo) {
  __shared__ float Bsh[Ln][NST], Csh[Ln][NST];
  int b      = blockIdx.x / (NIN / 256);
  int dchunk = blockIdx.x % (NIN / 256);
  int t = threadIdx.x;
  if (t < Ln * NST) {
    int p = t / NST, n = t % NST;
    const float* row = dbc + (size_t)(b * Ln + p) * (DTR + 2 * NST);
    Bsh[p][n] = row[DTR + n];
    Csh[p][n] = row[DTR + NST + n];
  }
  __syncthreads();
  int d = dchunk * 256 + t;
  float Ar[NST];
  #pragma unroll
  for (int n = 0; n < NST; ++n) Ar[n] = -expf(A_log[(size_t)d * NST + n]);
  float s[NST];
  #pragma unroll
  for (int n = 0; n < NST; ++n) s[n] = 0.0f;
  float Dv = Dp[d];
  for (int p = 0; p < Ln; ++p) {
    size_t off = (size_t)(b * Ln + p) * NIN + d;
    float dl = delta[off];
    float u  = xcb[off];
    float du = dl * u;
    float y = 0.0f;
    #pragma unroll
    for (int n = 0; n < NST; ++n) {
      float dA = expf(dl * Ar[n]);
      s[n] = dA * s[n] + du * Bsh[p][n];
      y += s[n] * Csh[p][n];
    }
    float zv = xz[(size_t)(b * Ln + p) * (2 * NIN) + NIN + d];
    float sz = zv / (1.0f + expf(-zv));
    float yv = (y + u * Dv) * sz;
    unsigned short hi, lo;
    split_bf(yv, hi, lo);
    yhi[off] = hi; ylo[off] = lo;
  }
}

// ---------------- transpose + bilinear resize (3,3) -> (24,12) ----------------
__global__ __launch_bounds__(256) void resize_kernel(const float* __restrict__ o9,
                                                     float* __restrict__ out) {
  int idx = blockIdx.x * 256 + threadIdx.x;
  if (idx >= Bn * Cn * Hn) return;
  int y  = idx % Hn;
  int bc = idx / Hn;
  int c = bc % Cn, b = bc / Cn;
  float v[9];
  #pragma unroll
  for (int p = 0; p < 9; ++p) v[p] = o9[(size_t)(b * Ln + p) * Cn + c];
  float fy  = (y + 0.5f) * 0.125f - 0.5f;
  float fyf = floorf(fy);
  float wy  = fy - fyf;
  int y0 = (int)fyf, y1 = y0 + 1;
  y0 = min(2, max(0, y0)); y1 = min(2, max(0, y1));
  float rr[3];
  #pragma unroll
  for (int j = 0; j < 3; ++j) rr[j] = v[y0 * 3 + j] * (1.0f - wy) + v[y1 * 3 + j] * wy;
  float ov[12];
  #pragma unroll
  for (int xo = 0; xo < 12; ++xo) {
    float fx  = (xo + 0.5f) * 0.25f - 0.5f;
    float fxf = floorf(fx);
    float wx  = fx - fxf;
    int x0 = (int)fxf, x1 = x0 + 1;
    x0 = min(2, max(0, x0)); x1 = min(2, max(0, x1));
    ov[xo] = rr[x0] * (1.0f - wx) + rr[x1] * wx;
  }
  float4* op = reinterpret_cast<float4*>(out + (size_t)idx * 12);
  op[0] = make_float4(ov[0], ov[1], ov[2],  ov[3]);
  op[1] = make_float4(ov[4], ov[5], ov[6],  ov[7]);
  op[2] = make_float4(ov[8], ov[9], ov[10], ov[11]);
}

extern "C" void kernel_launch(void* const* d_in, const int* in_sizes, int n_in,
                              void* d_out, int out_size, void* d_ws, size_t ws_size,
                              hipStream_t stream) {
  const float* x        = (const float*)d_in[0];
  const float* pe_w     = (const float*)d_in[1];
  const float* pe_b     = (const float*)d_in[2];
  const float* ln_g     = (const float*)d_in[3];
  const float* ln_b     = (const float*)d_in[4];
  const float* in_w     = (const float*)d_in[5];
  const float* conv_w   = (const float*)d_in[6];
  const float* conv_b   = (const float*)d_in[7];
  const float* A_log    = (const float*)d_in[8];
  const float* xproj_w  = (const float*)d_in[9];
  const float* dtproj_w = (const float*)d_in[10];
  const float* dtproj_b = (const float*)d_in[11];
  const float* D_param  = (const float*)d_in[12];
  const float* out_w    = (const float*)d_in[13];
  float* out = (float*)d_out;
  char* ws = (char*)d_ws;

  size_t o = 0;
  auto alloc = [&](size_t bytes) { size_t r = o; o += (bytes + 255) & ~(size_t)255; return r; };
  unsigned short* tok_hi = (unsigned short*)(ws + alloc((size_t)Mn * Cn * 2));
  unsigned short* tok_lo = (unsigned short*)(ws + alloc((size_t)Mn * Cn * 2));
  unsigned short* peT_hi = (unsigned short*)(ws + alloc((size_t)HID * Cn * 2));
  unsigned short* peT_lo = (unsigned short*)(ws + alloc((size_t)HID * Cn * 2));
  float*          t1     = (float*)(ws + alloc((size_t)Mn * HID * 4));
  unsigned short* inT_hi = (unsigned short*)(ws + alloc((size_t)2 * NIN * HID * 2));
  unsigned short* inT_lo = (unsigned short*)(ws + alloc((size_t)2 * NIN * HID * 2));
  unsigned short* h_hi   = (unsigned short*)(ws + alloc((size_t)Mn * HID * 2));
  unsigned short* h_lo   = (unsigned short*)(ws + alloc((size_t)Mn * HID * 2));
  float*          xz     = (float*)(ws + alloc((size_t)Mn * 2 * NIN * 4));
  float*          xc     = (float*)(ws + alloc((size_t)Mn * NIN * 4));
  float*          dbc    = (float*)(ws + alloc((size_t)Mn * (DTR + 2 * NST) * 4));
  float*          delta  = (float*)(ws + alloc((size_t)Mn * NIN * 4));
  unsigned short* outT_hi= (unsigned short*)(ws + alloc((size_t)Cn * NIN * 2));
  unsigned short* outT_lo= (unsigned short*)(ws + alloc((size_t)Cn * NIN * 2));
  unsigned short* ya_hi  = (unsigned short*)(ws + alloc((size_t)Mn * NIN * 2));
  unsigned short* ya_lo  = (unsigned short*)(ws + alloc((size_t)Mn * NIN * 2));
  float*          o9     = (float*)(ws + alloc((size_t)Mn * Cn * 4));

  // weight conversions (independent of activations)
  tconv_kernel<<<dim3(HID / 32, Cn / 32), 256, 0, stream>>>(pe_w, Cn, HID, peT_hi, peT_lo);
  tconv_kernel<<<dim3(2 * NIN / 32, HID / 32), 256, 0, stream>>>(in_w, HID, 2 * NIN, inT_hi, inT_lo);
  tconv_kernel<<<dim3(Cn / 32, NIN / 32), 256, 0, stream>>>(out_w, NIN, Cn, outT_hi, outT_lo);

  pool_kernel<<<(Bn * Cn) / 256, 256, 0, stream>>>(x, tok_hi, tok_lo);
  mgemm_kernel<1><<<dim3(HID / 128, Mn / 128), 256, 0, stream>>>(
      tok_hi, tok_lo, peT_hi, peT_lo, pe_b, t1, Mn, HID, Cn);
  ln_kernel<<<Mn, 256, 0, stream>>>(t1, ln_g, ln_b, h_hi, h_lo);
  mgemm_kernel<0><<<dim3(2 * NIN / 128, Mn / 128), 256, 0, stream>>>(
      h_hi, h_lo, inT_hi, inT_lo, nullptr, xz, Mn, 2 * NIN, HID);
  conv_silu_kernel<<<(Mn * NIN) / 256, 256, 0, stream>>>(xz, conv_w, conv_b, xc);
  gemm_kernel<0><<<dim3(2, Mn / 64), 256, 0, stream>>>(
      xc, NIN, xproj_w, nullptr, dbc, Mn, DTR + 2 * NST, NIN);
  gemm_kernel<1><<<dim3(NIN / 64, Mn / 64), 256, 0, stream>>>(
      dbc, DTR + 2 * NST, dtproj_w, dtproj_b, delta, Mn, NIN, DTR);
  scan_kernel<<<Bn * (NIN / 256), 256, 0, stream>>>(
      delta, dbc, xc, A_log, D_param, xz, ya_hi, ya_lo);
  mgemm_kernel<0><<<dim3(Cn / 128, Mn / 128), 256, 0, stream>>>(
      ya_hi, ya_lo, outT_hi, outT_lo, nullptr, o9, Mn, Cn, NIN);
  resize_kernel<<<(Bn * Cn * Hn) / 256, 256, 0, stream>>>(o9, out);
}